// Round 1
// 286.214 us; speedup vs baseline: 1.0317x; 1.0317x over previous
//
#include <hip/hip_runtime.h>
#include <math.h>

#define BATCH   8
#define CCH     512
#define NHEADS  8
#define HD      64
#define NGROUPS 32
#define CPG     16
#define NSP     4096      // H*W
#define O1      1536      // 3*C

typedef __attribute__((ext_vector_type(8))) short          short8;
typedef __attribute__((ext_vector_type(8))) unsigned short ushort8;
typedef __attribute__((ext_vector_type(4))) unsigned short ushort4v;
typedef __attribute__((ext_vector_type(4))) float          float4v;

#define GLOAD_LDS16(g, s) __builtin_amdgcn_global_load_lds(                   \
    (const __attribute__((address_space(1))) void*)(g),                       \
    (__attribute__((address_space(3))) void*)(s), 16, 0, 0)

// ---------------------------------------------------------------------------
__device__ __forceinline__ float phi_act(float v) {   // elu(x)+1
    return v > 0.f ? v + 1.f : __expf(v);
}
__device__ __forceinline__ unsigned short f2bf(float f) {  // RNE fp32->bf16
    union { float f; unsigned int u; } c; c.f = f;
    unsigned int u = c.u;
    u += 0x7fffu + ((u >> 16) & 1u);
    return (unsigned short)(u >> 16);
}
__device__ __forceinline__ float bf2f(unsigned short s) {
    union { unsigned int u; float f; } c; c.u = ((unsigned int)s) << 16;
    return c.f;
}

// BK=64 LDS swizzle (rows of 128 B = 8 chunks of 16 B):
//  chunk c of row r lives at physical chunk c ^ (r & 7).
//  Staging: 1KB slab = 8 rows; lane ln writes physical (row=ln>>3, chunk=ln&7)
//    so it fetches GLOBAL chunk (ln&7) ^ (ln>>3).
//  Fragment read (quad,lm,kk): logical chunk kk*4+quad of row rb+lm (rb%16==0)
//    -> physical chunk (kk*4+quad) ^ (lm&7).  Worst 2 lanes/bank-group = free.

// ---------------------------------------------------------------------------
// Kernel 1: GroupNorm statistics -> per-(b,c) scale/shift
__global__ __launch_bounds__(256) void gn_stats(const float* __restrict__ x,
                                                const float* __restrict__ gamma,
                                                const float* __restrict__ beta,
                                                float* __restrict__ ss) {
    const int bg = blockIdx.x;
    const int t  = threadIdx.x;
    const float* base = x + (size_t)bg * (CPG * NSP);
    float s = 0.f, s2 = 0.f;
    #pragma unroll 4
    for (int i = 0; i < 64; ++i) {
        float4 v = *(const float4*)(base + (i * 256 + t) * 4);
        s  += v.x + v.y + v.z + v.w;
        s2 += v.x * v.x + v.y * v.y + v.z * v.z + v.w * v.w;
    }
    __shared__ float r1[256], r2[256];
    r1[t] = s; r2[t] = s2;
    __syncthreads();
    for (int off = 128; off > 0; off >>= 1) {
        if (t < off) { r1[t] += r1[t + off]; r2[t] += r2[t + off]; }
        __syncthreads();
    }
    if (t < CPG) {
        const float inv = 1.f / 65536.f;
        float mean = r1[0] * inv;
        float var  = r2[0] * inv - mean * mean;
        float rstd = rsqrtf(var + 1e-5f);
        int b = bg / NGROUPS, g = bg % NGROUPS;
        int c = g * CPG + t;
        float sc = gamma[c] * rstd;
        float sh = beta[c] - mean * sc;
        ss[(b * CCH + c) * 2]     = sc;
        ss[(b * CCH + c) * 2 + 1] = sh;
    }
}

// ---------------------------------------------------------------------------
// Kernel 2: weights fp32 -> bf16; block 0 also zeroes ksum (atomic target).
__global__ __launch_bounds__(256) void conv_w(const float* __restrict__ qw,
                                              const float* __restrict__ pw,
                                              unsigned short* __restrict__ qwb,
                                              unsigned short* __restrict__ pwb,
                                              float* __restrict__ ksum) {
    int i = (blockIdx.x * 256 + threadIdx.x) * 4;
    if (i < O1 * CCH) {
        float4 v = *(const float4*)(qw + i);
        unsigned short o[4] = {f2bf(v.x), f2bf(v.y), f2bf(v.z), f2bf(v.w)};
        *(uint2*)(qwb + i) = *(uint2*)o;
    } else {
        int j = i - O1 * CCH;
        float4 v = *(const float4*)(pw + j);
        unsigned short o[4] = {f2bf(v.x), f2bf(v.y), f2bf(v.z), f2bf(v.w)};
        *(uint2*)(pwb + j) = *(uint2*)o;
    }
    if (blockIdx.x == 0) {
        float4 z = {0.f, 0.f, 0.f, 0.f};
        #pragma unroll
        for (int l = 0; l < 4; ++l)
            *(float4*)(ksum + (l * 256 + threadIdx.x) * 4) = z;
    }
}

// ---------------------------------------------------------------------------
// Kernel 3: xnT[b][n][c] bf16 = GroupNorm(x)[b][c][n] transposed.
__global__ __launch_bounds__(256) void xnT_kernel(const float* __restrict__ x,
                                                  const float* __restrict__ ss,
                                                  unsigned short* __restrict__ xnT) {
    const int n0 = blockIdx.x * 64, c0 = blockIdx.y * 64, b = blockIdx.z;
    const int t = threadIdx.x;
    __shared__ float tile[64][65];
    const float* xb  = x + ((size_t)b * CCH + c0) * NSP + n0;
    const float* ssb = ss + b * CCH * 2;

    const int lr = t / 16, lc = (t % 16) * 4;
    #pragma unroll
    for (int j = 0; j < 4; ++j) {
        int cr = j * 16 + lr;
        float4 v = *(const float4*)(xb + (size_t)cr * NSP + lc);
        float sc = ssb[(c0 + cr) * 2], sh = ssb[(c0 + cr) * 2 + 1];
        tile[cr][lc + 0] = v.x * sc + sh;
        tile[cr][lc + 1] = v.y * sc + sh;
        tile[cr][lc + 2] = v.z * sc + sh;
        tile[cr][lc + 3] = v.w * sc + sh;
    }
    __syncthreads();
    #pragma unroll
    for (int j = 0; j < 2; ++j) {
        int wd = j * 256 + t;
        int n  = wd >> 3;
        int cb = (wd & 7) * 8;
        ushort8 o;
        #pragma unroll
        for (int i = 0; i < 8; ++i) o[i] = f2bf(tile[cb + i][n]);
        *(ushort8*)(xnT + ((size_t)b * NSP + n0 + n) * CCH + c0 + cb) = o;
    }
}

// ---------------------------------------------------------------------------
// Kernel 4: q GEMM (BK=64). mfma(w, x) -> rows=o. phi, 8B stores qT[b][n][c].
__global__ __launch_bounds__(256) void gemm_q(const unsigned short* __restrict__ A,
                                              const unsigned short* __restrict__ Bt,
                                              const float* __restrict__ bias,
                                              unsigned short* __restrict__ qT) {
    const int n0 = blockIdx.x * 128;
    const int o0 = blockIdx.y * 128;
    const int b  = blockIdx.z;
    const int t  = threadIdx.x;
    const int wv = t >> 6, ln = t & 63;
    const int quad = ln >> 4, lm = ln & 15;
    const int wo = (wv >> 1) * 64, wn = (wv & 1) * 64;

    __shared__ __align__(16) unsigned short As[128 * 64];
    __shared__ __align__(16) unsigned short Bs[128 * 64];

    float4v acc[4][4];
    #pragma unroll
    for (int i = 0; i < 4; ++i)
        #pragma unroll
        for (int j = 0; j < 4; ++j) acc[i][j] = {0.f, 0.f, 0.f, 0.f};

    const unsigned short* aBase = A + (size_t)o0 * CCH;
    const unsigned short* bBase = Bt + ((size_t)b * NSP + n0) * CCH;

    const int srow8 = ln >> 3;                        // row within slab
    const int scs   = ((ln & 7) ^ srow8) * 8;         // staging inverse swizzle
    const int lmp   = (lm & 7);                       // fragment row parity

    for (int k0 = 0; k0 < CCH; k0 += 64) {
        __syncthreads();
        #pragma unroll
        for (int i = 0; i < 4; ++i) {
            int slab = wv + i * 4;                    // 0..15, 8 rows each
            GLOAD_LDS16(aBase + (size_t)(slab * 8 + srow8) * CCH + k0 + scs,
                        As + slab * 512);
            GLOAD_LDS16(bBase + (size_t)(slab * 8 + srow8) * CCH + k0 + scs,
                        Bs + slab * 512);
        }
        __syncthreads();
        #pragma unroll
        for (int kk = 0; kk < 2; ++kk) {
            const int sc8 = ((kk * 4 + quad) ^ lmp) * 8;
            short8 fw[4], fx[4];
            #pragma unroll
            for (int i = 0; i < 4; ++i)
                fw[i] = *(const short8*)(As + (wo + i * 16 + lm) * 64 + sc8);
            #pragma unroll
            for (int j = 0; j < 4; ++j)
                fx[j] = *(const short8*)(Bs + (wn + j * 16 + lm) * 64 + sc8);
            #pragma unroll
            for (int i = 0; i < 4; ++i)
                #pragma unroll
                for (int j = 0; j < 4; ++j)
                    acc[i][j] = __builtin_amdgcn_mfma_f32_16x16x32_bf16(
                        fw[i], fx[j], acc[i][j], 0, 0, 0);
        }
    }

    // rows=o (quad*4+r), cols=n (lm). phi, store 4 consecutive o.
    #pragma unroll
    for (int i = 0; i < 4; ++i) {
        int ob = o0 + wo + i * 16 + quad * 4;
        float4 b4 = *(const float4*)(bias + ob);
        float bs[4] = {b4.x, b4.y, b4.z, b4.w};
        #pragma unroll
        for (int j = 0; j < 4; ++j) {
            int n = n0 + wn + j * 16 + lm;
            ushort4v pk;
            #pragma unroll
            for (int r = 0; r < 4; ++r)
                pk[r] = f2bf(phi_act(acc[i][j][r] + bs[r]));
            *(ushort4v*)(qT + ((size_t)b * NSP + n) * CCH + ob) = pk;
        }
    }
}

// ---------------------------------------------------------------------------
// Kernel 5 (FUSED): k/v GEMM for ONE head + in-block kv outer product.
//   grid = (n-chunk 32, head 8, batch 8).  Per block:
//     - 128x128x512 GEMM: o-tile = {64 k-rows, 64 v-rows} of head h
//     - epilogue: bias + phi(k) -> bf16 tile [c][128n] in LDS (XOR-swizzled)
//     - 64 extra MFMAs: kvp[chunk][bh][e][d] += over this chunk's 128 n
//     - ksum atomics from the fp32 phi values
//   kb/vb never touch HBM; kv_mfma kernel deleted.
__global__ __launch_bounds__(256) void gemm_kv(const unsigned short* __restrict__ A,
                                               const unsigned short* __restrict__ Bt,
                                               const float* __restrict__ bias,
                                               float* __restrict__ ksum,
                                               float* __restrict__ kvp) {
    const int n0 = blockIdx.x * 128;
    const int h  = blockIdx.y;
    const int b  = blockIdx.z;
    const int t  = threadIdx.x;
    const int wv = t >> 6, ln = t & 63;
    const int quad = ln >> 4, lm = ln & 15;
    const int wo = (wv >> 1) * 64, wn = (wv & 1) * 64;

    // 32 KB shared: GEMM staging (As = sh, Bs = sh+8192), then reused as the
    // 128x128 bf16 [c][n] tile for the kv outer product.
    __shared__ __align__(16) unsigned short sh[2 * 128 * 64];

    float4v acc[4][4];
    #pragma unroll
    for (int i = 0; i < 4; ++i)
        #pragma unroll
        for (int j = 0; j < 4; ++j) acc[i][j] = {0.f, 0.f, 0.f, 0.f};

    const unsigned short* aK = A + (size_t)(512 + h * 64) * CCH;   // k rows
    const unsigned short* aV = A + (size_t)(1024 + h * 64) * CCH;  // v rows
    const unsigned short* bBase = Bt + ((size_t)b * NSP + n0) * CCH;

    const int srow8 = ln >> 3;
    const int scs   = ((ln & 7) ^ srow8) * 8;
    const int lmp   = (lm & 7);

    for (int k0 = 0; k0 < CCH; k0 += 64) {
        __syncthreads();
        #pragma unroll
        for (int i = 0; i < 4; ++i) {
            int slab = wv + i * 4;                    // 0..15; <8 = k, >=8 = v
            const unsigned short* ab = (slab < 8)
                ? aK + (size_t)(slab * 8 + srow8) * CCH
                : aV + (size_t)((slab - 8) * 8 + srow8) * CCH;
            GLOAD_LDS16(ab + k0 + scs, sh + slab * 512);
            GLOAD_LDS16(bBase + (size_t)(slab * 8 + srow8) * CCH + k0 + scs,
                        sh + 8192 + slab * 512);
        }
        __syncthreads();
        #pragma unroll
        for (int kk = 0; kk < 2; ++kk) {
            const int sc8 = ((kk * 4 + quad) ^ lmp) * 8;
            short8 fw[4], fx[4];
            #pragma unroll
            for (int i = 0; i < 4; ++i)
                fw[i] = *(const short8*)(sh + (wo + i * 16 + lm) * 64 + sc8);
            #pragma unroll
            for (int j = 0; j < 4; ++j)
                fx[j] = *(const short8*)(sh + 8192 + (wn + j * 16 + lm) * 64 + sc8);
            #pragma unroll
            for (int i = 0; i < 4; ++i)
                #pragma unroll
                for (int j = 0; j < 4; ++j)
                    acc[i][j] = __builtin_amdgcn_mfma_f32_16x16x32_bf16(
                        fx[j], fw[i], acc[i][j], 0, 0, 0);
        }
    }

    // ---- epilogue 1: bias + phi(k), write bf16 tile [c][n] to LDS ----
    // acc: rows=n (quad*4+r), cols=c (lm); c = wo+i*16+lm (0..63 k, 64..127 v)
    // LDS tile: row c, 128 n = 16 chunks of 8 elems; phys chunk = lchunk^(c&15)
    __syncthreads();                                  // done reading As/Bs
    const bool isk = (wv < 2);                        // wo==0 -> k rows
    const float* bptr = bias + (isk ? 512 : 1024) + h * 64;
    float ksp[4] = {0.f, 0.f, 0.f, 0.f};
    #pragma unroll
    for (int i = 0; i < 4; ++i) {
        float bs = bptr[i * 16 + lm];
        int row = wo + i * 16 + lm;                   // 0..127
        #pragma unroll
        for (int j = 0; j < 4; ++j) {
            int n = wn + j * 16 + quad * 4;
            ushort4v pk;
            #pragma unroll
            for (int r = 0; r < 4; ++r) {
                float v = acc[i][j][r] + bs;
                if (isk) { v = phi_act(v); ksp[i] += v; }
                pk[r] = f2bf(v);
            }
            int idx = row * 128 + ((((n >> 3) ^ (row & 15)) << 3) | (n & 7));
            *(ushort4v*)(sh + idx) = pk;
        }
    }
    // ksum partials (fp32, pre-round) -> quad-reduce -> atomic
    if (isk) {
        #pragma unroll
        for (int i = 0; i < 4; ++i) {
            float s = ksp[i];
            s += __shfl_xor(s, 16);
            s += __shfl_xor(s, 32);
            if (quad == 0)
                atomicAdd(ksum + b * CCH + h * 64 + i * 16 + lm, s);
        }
    }
    __syncthreads();

    // ---- epilogue 2: kv partial = k_tile^T . v_tile over 128 n ----
    const int wd = (wv >> 1) * 32, we = (wv & 1) * 32;
    float4v acc2[2][2];
    #pragma unroll
    for (int i = 0; i < 2; ++i)
        #pragma unroll
        for (int j = 0; j < 2; ++j) acc2[i][j] = {0.f, 0.f, 0.f, 0.f};

    #pragma unroll
    for (int ks = 0; ks < 4; ++ks) {
        short8 ka[2], vbf[2];
        #pragma unroll
        for (int i2 = 0; i2 < 2; ++i2) {
            int row = wd + i2 * 16 + lm;              // k rows 0..63
            ka[i2] = *(const short8*)(sh + row * 128 +
                                      (((ks * 4 + quad) ^ (row & 15)) << 3));
        }
        #pragma unroll
        for (int j2 = 0; j2 < 2; ++j2) {
            int row = 64 + we + j2 * 16 + lm;         // v rows 64..127
            vbf[j2] = *(const short8*)(sh + row * 128 +
                                       (((ks * 4 + quad) ^ (row & 15)) << 3));
        }
        #pragma unroll
        for (int i2 = 0; i2 < 2; ++i2)
            #pragma unroll
            for (int j2 = 0; j2 < 2; ++j2)
                acc2[i2][j2] = __builtin_amdgcn_mfma_f32_16x16x32_bf16(
                    ka[i2], vbf[j2], acc2[i2][j2], 0, 0, 0);
    }

    // rows=d (quad*4+r), cols=e (lm) -> store [e][d], 4 consecutive d.
    const int chunk = blockIdx.x;
    const int bh = b * 8 + h;
    #pragma unroll
    for (int i2 = 0; i2 < 2; ++i2)
        #pragma unroll
        for (int j2 = 0; j2 < 2; ++j2) {
            int e = we + j2 * 16 + lm;
            int d = wd + i2 * 16 + quad * 4;
            float4 r = {acc2[i2][j2][0], acc2[i2][j2][1],
                        acc2[i2][j2][2], acc2[i2][j2][3]};
            *(float4*)(kvp + ((size_t)(chunk * 64 + bh) * 64 + e) * 64 + d) = r;
        }
}

// ---------------------------------------------------------------------------
// Kernel 7: reduce 32 chunk partials -> kvTb[bh][e][d] bf16.
__global__ __launch_bounds__(256) void kv_reduce(const float* __restrict__ kvp,
                                                 unsigned short* __restrict__ kvTb) {
    int idx4 = (blockIdx.x * 256 + threadIdx.x) * 4;   // over 64*64*64
    float4 s = {0.f, 0.f, 0.f, 0.f};
    #pragma unroll
    for (int p = 0; p < 32; ++p) {
        float4 v = *(const float4*)(kvp + (size_t)p * (64 * 64 * 64) + idx4);
        s.x += v.x; s.y += v.y; s.z += v.z; s.w += v.w;
    }
    ushort4v o = {f2bf(s.x), f2bf(s.y), f2bf(s.z), f2bf(s.w)};
    *(ushort4v*)(kvTb + idx4) = o;
}

// ---------------------------------------------------------------------------
// Kernel 8: attn via MFMA. out[n][e] = (sum_d qT[n][d]*kvT[e][d]) / den[n].
__global__ __launch_bounds__(256) void attn_mfma(const unsigned short* __restrict__ qT,
                                                 const unsigned short* __restrict__ kvTb,
                                                 const float* __restrict__ ksum,
                                                 unsigned short* __restrict__ attnT) {
    const int n0 = blockIdx.x * 256;
    const int bh = blockIdx.y;
    const int b = bh >> 3, h = bh & 7;
    const int t = threadIdx.x;
    const int wv = t >> 6, ln = t & 63;
    const int quad = ln >> 4, lm = ln & 15;
    const int nb = n0 + wv * 64;

    __shared__ __align__(16) unsigned short kvs[64 * 72];
    __shared__ float kss[64];

    #pragma unroll
    for (int l = 0; l < 2; ++l) {
        int ch = l * 256 + t;            // 512 chunks of 8 ushorts
        int e = ch >> 3, c8 = ch & 7;
        *(ushort8*)(kvs + e * 72 + c8 * 8) =
            *(const ushort8*)(kvTb + (size_t)bh * 4096 + ch * 8);
    }
    if (t < 64) kss[t] = ksum[b * CCH + h * 64 + t];
    __syncthreads();

    short8 bq[4][2];
    #pragma unroll
    for (int j = 0; j < 4; ++j)
        #pragma unroll
        for (int kk = 0; kk < 2; ++kk) {
            int n = nb + j * 16 + lm;
            bq[j][kk] = *(const short8*)(qT + ((size_t)b * NSP + n) * CCH +
                                         h * 64 + kk * 32 + quad * 8);
        }
    short8 ak[4][2];
    #pragma unroll
    for (int i = 0; i < 4; ++i)
        #pragma unroll
        for (int kk = 0; kk < 2; ++kk)
            ak[i][kk] = *(const short8*)(kvs + (i * 16 + lm) * 72 + kk * 32 + quad * 8);

    float4v acc[4][4];
    #pragma unroll
    for (int i = 0; i < 4; ++i)
        #pragma unroll
        for (int j = 0; j < 4; ++j) acc[i][j] = {0.f, 0.f, 0.f, 0.f};
    #pragma unroll
    for (int kk = 0; kk < 2; ++kk)
        #pragma unroll
        for (int i = 0; i < 4; ++i)
            #pragma unroll
            for (int j = 0; j < 4; ++j)
                acc[i][j] = __builtin_amdgcn_mfma_f32_16x16x32_bf16(
                    ak[i][kk], bq[j][kk], acc[i][j], 0, 0, 0);

    // denominators: den[n=nb+j*16+lm] = sum_d q[n][d]*ksum[d]
    float rden[4];
    #pragma unroll
    for (int j = 0; j < 4; ++j) {
        float dp = 0.f;
        #pragma unroll
        for (int kk = 0; kk < 2; ++kk)
            #pragma unroll
            for (int l = 0; l < 8; ++l)
                dp += bf2f((unsigned short)bq[j][kk][l]) * kss[kk * 32 + quad * 8 + l];
        dp += __shfl_xor(dp, 16);
        dp += __shfl_xor(dp, 32);
        rden[j] = 1.f / (dp + 1e-6f);
    }

    // rows=e (quad*4+r), cols=n (lm): 4 consecutive e -> 8B store to attnT[n][c]
    #pragma unroll
    for (int i = 0; i < 4; ++i) {
        int e = i * 16 + quad * 4;
        #pragma unroll
        for (int j = 0; j < 4; ++j) {
            int n = nb + j * 16 + lm;
            ushort4v pk;
            #pragma unroll
            for (int r = 0; r < 4; ++r)
                pk[r] = f2bf(acc[i][j][r] * rden[j]);
            *(ushort4v*)(attnT + ((size_t)b * NSP + n) * CCH + h * 64 + e) = pk;
        }
    }
}

// ---------------------------------------------------------------------------
// Kernel 9: proj GEMM (BK=64). mfma(attnT, w) -> rows=n. float4 bias+resid.
__global__ __launch_bounds__(256) void gemm_proj(const unsigned short* __restrict__ A,
                                                 const unsigned short* __restrict__ Bt,
                                                 const float* __restrict__ bias,
                                                 const float* __restrict__ resid,
                                                 float* __restrict__ outF) {
    const int n0 = blockIdx.x * 128;
    const int o0 = blockIdx.y * 128;
    const int b  = blockIdx.z;
    const int t  = threadIdx.x;
    const int wv = t >> 6, ln = t & 63;
    const int quad = ln >> 4, lm = ln & 15;
    const int wo = (wv >> 1) * 64, wn = (wv & 1) * 64;

    __shared__ __align__(16) unsigned short As[128 * 64];
    __shared__ __align__(16) unsigned short Bs[128 * 64];

    float4v acc[4][4];
    #pragma unroll
    for (int i = 0; i < 4; ++i)
        #pragma unroll
        for (int j = 0; j < 4; ++j) acc[i][j] = {0.f, 0.f, 0.f, 0.f};

    const unsigned short* aBase = A + (size_t)o0 * CCH;
    const unsigned short* bBase = Bt + ((size_t)b * NSP + n0) * CCH;

    const int srow8 = ln >> 3;
    const int scs   = ((ln & 7) ^ srow8) * 8;
    const int lmp   = (lm & 7);

    for (int k0 = 0; k0 < CCH; k0 += 64) {
        __syncthreads();
        #pragma unroll
        for (int i = 0; i < 4; ++i) {
            int slab = wv + i * 4;
            GLOAD_LDS16(aBase + (size_t)(slab * 8 + srow8) * CCH + k0 + scs,
                        As + slab * 512);
            GLOAD_LDS16(bBase + (size_t)(slab * 8 + srow8) * CCH + k0 + scs,
                        Bs + slab * 512);
        }
        __syncthreads();
        #pragma unroll
        for (int kk = 0; kk < 2; ++kk) {
            const int sc8 = ((kk * 4 + quad) ^ lmp) * 8;
            short8 fw[4], fx[4];
            #pragma unroll
            for (int i = 0; i < 4; ++i)
                fw[i] = *(const short8*)(As + (wo + i * 16 + lm) * 64 + sc8);
            #pragma unroll
            for (int j = 0; j < 4; ++j)
                fx[j] = *(const short8*)(Bs + (wn + j * 16 + lm) * 64 + sc8);
            #pragma unroll
            for (int i = 0; i < 4; ++i)
                #pragma unroll
                for (int j = 0; j < 4; ++j)
                    acc[i][j] = __builtin_amdgcn_mfma_f32_16x16x32_bf16(
                        fx[j], fw[i], acc[i][j], 0, 0, 0);
        }
    }

    // rows=n (quad*4+r), cols=o (lm). float4 bias+resid epilogue.
    #pragma unroll
    for (int i = 0; i < 4; ++i) {
        int o = o0 + wo + i * 16 + lm;
        float bs = bias[o];
        #pragma unroll
        for (int j = 0; j < 4; ++j) {
            int n = n0 + wn + j * 16 + quad * 4;
            size_t off = ((size_t)b * CCH + o) * NSP + n;
            float4 rv = *(const float4*)(resid + off);
            float4 w = {acc[i][j][0] + bs + rv.x, acc[i][j][1] + bs + rv.y,
                        acc[i][j][2] + bs + rv.z, acc[i][j][3] + bs + rv.w};
            *(float4*)(outF + off) = w;
        }
    }
}

// ---------------------------------------------------------------------------
extern "C" void kernel_launch(void* const* d_in, const int* in_sizes, int n_in,
                              void* d_out, int out_size, void* d_ws, size_t ws_size,
                              hipStream_t stream) {
    const float* x      = (const float*)d_in[0];
    const float* gamma  = (const float*)d_in[1];
    const float* beta   = (const float*)d_in[2];
    const float* qkv_w  = (const float*)d_in[3];
    const float* qkv_b  = (const float*)d_in[4];
    const float* proj_w = (const float*)d_in[5];
    const float* proj_b = (const float*)d_in[6];
    float* out = (float*)d_out;

    // workspace layout (float units)
    float* ws   = (float*)d_ws;
    float* ss   = ws;                                   //    8192
    float* ksum = ss + 8192;                            //    4096
    float* kvp  = ksum + 4096;                          // 32*64*64*64
    unsigned short* xnT   = (unsigned short*)(kvp + (size_t)32 * 64 * 64 * 64);
    unsigned short* qT    = xnT + (size_t)BATCH * NSP * CCH;
    unsigned short* attnT = qT  + (size_t)BATCH * NSP * CCH;
    unsigned short* kvTb  = attnT + (size_t)BATCH * NSP * CCH;
    unsigned short* wqb   = kvTb + (size_t)64 * 64 * 64;
    unsigned short* wpb   = wqb + (size_t)O1 * CCH;

    gn_stats<<<BATCH * NGROUPS, 256, 0, stream>>>(x, gamma, beta, ss);
    conv_w<<<(O1 * CCH + CCH * CCH) / 4 / 256, 256, 0, stream>>>(qkv_w, proj_w, wqb, wpb, ksum);
    xnT_kernel<<<dim3(NSP / 64, CCH / 64, BATCH), 256, 0, stream>>>(x, ss, xnT);

    gemm_q <<<dim3(NSP / 128, 4, BATCH), 256, 0, stream>>>(wqb, xnT, qkv_b, qT);
    gemm_kv<<<dim3(NSP / 128, NHEADS, BATCH), 256, 0, stream>>>(wqb, xnT, qkv_b, ksum, kvp);

    kv_reduce<<<256, 256, 0, stream>>>(kvp, kvTb);
    attn_mfma<<<dim3(NSP / 256, 64), 256, 0, stream>>>(qT, kvTb, ksum, attnT);

    gemm_proj<<<dim3(NSP / 128, CCH / 128, BATCH), 256, 0, stream>>>(
        wpb, attnT, proj_b, x, out);
}

// Round 2
// 283.300 us; speedup vs baseline: 1.0424x; 1.0103x over previous
//
#include <hip/hip_runtime.h>
#include <math.h>

#define BATCH   8
#define CCH     512
#define NHEADS  8
#define HD      64
#define NGROUPS 32
#define CPG     16
#define NSP     4096      // H*W
#define O1      1536      // 3*C

typedef __attribute__((ext_vector_type(8))) short          short8;
typedef __attribute__((ext_vector_type(8))) unsigned short ushort8;
typedef __attribute__((ext_vector_type(4))) unsigned short ushort4v;
typedef __attribute__((ext_vector_type(4))) float          float4v;

#define GLOAD_LDS16(g, s) __builtin_amdgcn_global_load_lds(                   \
    (const __attribute__((address_space(1))) void*)(g),                       \
    (__attribute__((address_space(3))) void*)(s), 16, 0, 0)

// ---------------------------------------------------------------------------
__device__ __forceinline__ float phi_act(float v) {   // elu(x)+1
    return v > 0.f ? v + 1.f : __expf(v);
}
__device__ __forceinline__ unsigned short f2bf(float f) {  // RNE fp32->bf16
    union { float f; unsigned int u; } c; c.f = f;
    unsigned int u = c.u;
    u += 0x7fffu + ((u >> 16) & 1u);
    return (unsigned short)(u >> 16);
}
__device__ __forceinline__ float bf2f(unsigned short s) {
    union { unsigned int u; float f; } c; c.u = ((unsigned int)s) << 16;
    return c.f;
}

// BK=64 LDS swizzle (rows of 128 B = 8 chunks of 16 B):
//  chunk c of row r lives at physical chunk c ^ (r & 7).
//  Staging: 1KB slab = 8 rows; lane ln writes physical (row=ln>>3, chunk=ln&7)
//    so it fetches GLOBAL chunk (ln&7) ^ (ln>>3).
//  Fragment read (quad,lm,kk): logical chunk kk*4+quad of row rb+lm (rb%16==0)
//    -> physical chunk (kk*4+quad) ^ (lm&7).  Worst 2 lanes/bank-group = free.

// ---------------------------------------------------------------------------
// Kernel 1: GroupNorm statistics -> per-(b,c) scale/shift
__global__ __launch_bounds__(256) void gn_stats(const float* __restrict__ x,
                                                const float* __restrict__ gamma,
                                                const float* __restrict__ beta,
                                                float* __restrict__ ss) {
    const int bg = blockIdx.x;
    const int t  = threadIdx.x;
    const float* base = x + (size_t)bg * (CPG * NSP);
    float s = 0.f, s2 = 0.f;
    #pragma unroll 4
    for (int i = 0; i < 64; ++i) {
        float4 v = *(const float4*)(base + (i * 256 + t) * 4);
        s  += v.x + v.y + v.z + v.w;
        s2 += v.x * v.x + v.y * v.y + v.z * v.z + v.w * v.w;
    }
    __shared__ float r1[256], r2[256];
    r1[t] = s; r2[t] = s2;
    __syncthreads();
    for (int off = 128; off > 0; off >>= 1) {
        if (t < off) { r1[t] += r1[t + off]; r2[t] += r2[t + off]; }
        __syncthreads();
    }
    if (t < CPG) {
        const float inv = 1.f / 65536.f;
        float mean = r1[0] * inv;
        float var  = r2[0] * inv - mean * mean;
        float rstd = rsqrtf(var + 1e-5f);
        int b = bg / NGROUPS, g = bg % NGROUPS;
        int c = g * CPG + t;
        float sc = gamma[c] * rstd;
        float sh = beta[c] - mean * sc;
        ss[(b * CCH + c) * 2]     = sc;
        ss[(b * CCH + c) * 2 + 1] = sh;
    }
}

// ---------------------------------------------------------------------------
// Kernel 2: weights fp32 -> bf16; blocks 0..31 zero den, block 0 zeroes ksum.
__global__ __launch_bounds__(256) void conv_w(const float* __restrict__ qw,
                                              const float* __restrict__ pw,
                                              unsigned short* __restrict__ qwb,
                                              unsigned short* __restrict__ pwb,
                                              float* __restrict__ ksum,
                                              float* __restrict__ den) {
    int i = (blockIdx.x * 256 + threadIdx.x) * 4;
    if (i < O1 * CCH) {
        float4 v = *(const float4*)(qw + i);
        unsigned short o[4] = {f2bf(v.x), f2bf(v.y), f2bf(v.z), f2bf(v.w)};
        *(uint2*)(qwb + i) = *(uint2*)o;
    } else {
        int j = i - O1 * CCH;
        float4 v = *(const float4*)(pw + j);
        unsigned short o[4] = {f2bf(v.x), f2bf(v.y), f2bf(v.z), f2bf(v.w)};
        *(uint2*)(pwb + j) = *(uint2*)o;
    }
    float4 z = {0.f, 0.f, 0.f, 0.f};
    if (blockIdx.x == 0) {
        #pragma unroll
        for (int l = 0; l < 4; ++l)
            *(float4*)(ksum + (l * 256 + threadIdx.x) * 4) = z;
    }
    if (blockIdx.x < 32)
        *(float4*)(den + (blockIdx.x * 256 + threadIdx.x) * 4) = z;
}

// ---------------------------------------------------------------------------
// Kernel 3: xnT[b][n][c] bf16 = GroupNorm(x)[b][c][n] transposed.
__global__ __launch_bounds__(256) void xnT_kernel(const float* __restrict__ x,
                                                  const float* __restrict__ ss,
                                                  unsigned short* __restrict__ xnT) {
    const int n0 = blockIdx.x * 64, c0 = blockIdx.y * 64, b = blockIdx.z;
    const int t = threadIdx.x;
    __shared__ float tile[64][65];
    const float* xb  = x + ((size_t)b * CCH + c0) * NSP + n0;
    const float* ssb = ss + b * CCH * 2;

    const int lr = t / 16, lc = (t % 16) * 4;
    #pragma unroll
    for (int j = 0; j < 4; ++j) {
        int cr = j * 16 + lr;
        float4 v = *(const float4*)(xb + (size_t)cr * NSP + lc);
        float sc = ssb[(c0 + cr) * 2], sh = ssb[(c0 + cr) * 2 + 1];
        tile[cr][lc + 0] = v.x * sc + sh;
        tile[cr][lc + 1] = v.y * sc + sh;
        tile[cr][lc + 2] = v.z * sc + sh;
        tile[cr][lc + 3] = v.w * sc + sh;
    }
    __syncthreads();
    #pragma unroll
    for (int j = 0; j < 2; ++j) {
        int wd = j * 256 + t;
        int n  = wd >> 3;
        int cb = (wd & 7) * 8;
        ushort8 o;
        #pragma unroll
        for (int i = 0; i < 8; ++i) o[i] = f2bf(tile[cb + i][n]);
        *(ushort8*)(xnT + ((size_t)b * NSP + n0 + n) * CCH + c0 + cb) = o;
    }
}

// ---------------------------------------------------------------------------
// Kernel 4: q GEMM (BK=64). mfma(w, x) -> rows=o. phi, 8B stores qT[b][n][c].
// Also accumulates den[b][n] = sum_c phi(q)[n][c] * ksum[b][c] (fp32 q values,
// pre-bf16-rounding) via per-block partial + atomicAdd.  MUST run after
// gemm_kv (ksum final).
__global__ __launch_bounds__(256) void gemm_q(const unsigned short* __restrict__ A,
                                              const unsigned short* __restrict__ Bt,
                                              const float* __restrict__ bias,
                                              const float* __restrict__ ksum,
                                              unsigned short* __restrict__ qT,
                                              float* __restrict__ den) {
    const int n0 = blockIdx.x * 128;
    const int o0 = blockIdx.y * 128;
    const int b  = blockIdx.z;
    const int t  = threadIdx.x;
    const int wv = t >> 6, ln = t & 63;
    const int quad = ln >> 4, lm = ln & 15;
    const int wo = (wv >> 1) * 64, wn = (wv & 1) * 64;

    __shared__ __align__(16) unsigned short As[128 * 64];
    __shared__ __align__(16) unsigned short Bs[128 * 64];
    __shared__ float kss[128];

    if (t < 32)
        *(float4*)(kss + t * 4) = *(const float4*)(ksum + b * CCH + o0 + t * 4);

    float4v acc[4][4];
    #pragma unroll
    for (int i = 0; i < 4; ++i)
        #pragma unroll
        for (int j = 0; j < 4; ++j) acc[i][j] = {0.f, 0.f, 0.f, 0.f};

    const unsigned short* aBase = A + (size_t)o0 * CCH;
    const unsigned short* bBase = Bt + ((size_t)b * NSP + n0) * CCH;

    const int srow8 = ln >> 3;                        // row within slab
    const int scs   = ((ln & 7) ^ srow8) * 8;         // staging inverse swizzle
    const int lmp   = (lm & 7);                       // fragment row parity

    for (int k0 = 0; k0 < CCH; k0 += 64) {
        __syncthreads();
        #pragma unroll
        for (int i = 0; i < 4; ++i) {
            int slab = wv + i * 4;                    // 0..15, 8 rows each
            GLOAD_LDS16(aBase + (size_t)(slab * 8 + srow8) * CCH + k0 + scs,
                        As + slab * 512);
            GLOAD_LDS16(bBase + (size_t)(slab * 8 + srow8) * CCH + k0 + scs,
                        Bs + slab * 512);
        }
        __syncthreads();
        #pragma unroll
        for (int kk = 0; kk < 2; ++kk) {
            const int sc8 = ((kk * 4 + quad) ^ lmp) * 8;
            short8 fw[4], fx[4];
            #pragma unroll
            for (int i = 0; i < 4; ++i)
                fw[i] = *(const short8*)(As + (wo + i * 16 + lm) * 64 + sc8);
            #pragma unroll
            for (int j = 0; j < 4; ++j)
                fx[j] = *(const short8*)(Bs + (wn + j * 16 + lm) * 64 + sc8);
            #pragma unroll
            for (int i = 0; i < 4; ++i)
                #pragma unroll
                for (int j = 0; j < 4; ++j)
                    acc[i][j] = __builtin_amdgcn_mfma_f32_16x16x32_bf16(
                        fw[i], fx[j], acc[i][j], 0, 0, 0);
        }
    }

    // rows=o (quad*4+r), cols=n (lm). phi, store 4 consecutive o; den partial.
    float denp[4] = {0.f, 0.f, 0.f, 0.f};
    #pragma unroll
    for (int i = 0; i < 4; ++i) {
        int ob = o0 + wo + i * 16 + quad * 4;
        float4 b4 = *(const float4*)(bias + ob);
        float bs[4] = {b4.x, b4.y, b4.z, b4.w};
        float4 k4 = *(const float4*)(kss + wo + i * 16 + quad * 4);
        float kf[4] = {k4.x, k4.y, k4.z, k4.w};
        #pragma unroll
        for (int j = 0; j < 4; ++j) {
            int n = n0 + wn + j * 16 + lm;
            ushort4v pk;
            #pragma unroll
            for (int r = 0; r < 4; ++r) {
                float qv = phi_act(acc[i][j][r] + bs[r]);
                pk[r] = f2bf(qv);
                denp[j] += qv * kf[r];
            }
            *(ushort4v*)(qT + ((size_t)b * NSP + n) * CCH + ob) = pk;
        }
    }
    #pragma unroll
    for (int j = 0; j < 4; ++j) {
        float s = denp[j];
        s += __shfl_xor(s, 16);
        s += __shfl_xor(s, 32);
        if (quad == 0)
            atomicAdd(den + (size_t)b * NSP + n0 + wn + j * 16 + lm, s);
    }
}

// ---------------------------------------------------------------------------
// Kernel 5 (FUSED): k/v GEMM for ONE head + in-block kv outer product.
//   grid = (n-chunk 32, head 8, batch 8).  Per block:
//     - 128x128x512 GEMM: o-tile = {64 k-rows, 64 v-rows} of head h
//     - epilogue: bias + phi(k) -> bf16 tile [c][128n] in LDS (XOR-swizzled)
//     - 16 extra MFMAs: kvp partial [d][e] over this chunk's 128 n
//     - ksum atomics from the fp32 phi values
__global__ __launch_bounds__(256) void gemm_kv(const unsigned short* __restrict__ A,
                                               const unsigned short* __restrict__ Bt,
                                               const float* __restrict__ bias,
                                               float* __restrict__ ksum,
                                               float* __restrict__ kvp) {
    const int n0 = blockIdx.x * 128;
    const int h  = blockIdx.y;
    const int b  = blockIdx.z;
    const int t  = threadIdx.x;
    const int wv = t >> 6, ln = t & 63;
    const int quad = ln >> 4, lm = ln & 15;
    const int wo = (wv >> 1) * 64, wn = (wv & 1) * 64;

    // 32 KB shared: GEMM staging (As = sh, Bs = sh+8192), then reused as the
    // 128x128 bf16 [c][n] tile for the kv outer product.
    __shared__ __align__(16) unsigned short sh[2 * 128 * 64];

    float4v acc[4][4];
    #pragma unroll
    for (int i = 0; i < 4; ++i)
        #pragma unroll
        for (int j = 0; j < 4; ++j) acc[i][j] = {0.f, 0.f, 0.f, 0.f};

    const unsigned short* aK = A + (size_t)(512 + h * 64) * CCH;   // k rows
    const unsigned short* aV = A + (size_t)(1024 + h * 64) * CCH;  // v rows
    const unsigned short* bBase = Bt + ((size_t)b * NSP + n0) * CCH;

    const int srow8 = ln >> 3;
    const int scs   = ((ln & 7) ^ srow8) * 8;
    const int lmp   = (lm & 7);

    for (int k0 = 0; k0 < CCH; k0 += 64) {
        __syncthreads();
        #pragma unroll
        for (int i = 0; i < 4; ++i) {
            int slab = wv + i * 4;                    // 0..15; <8 = k, >=8 = v
            const unsigned short* ab = (slab < 8)
                ? aK + (size_t)(slab * 8 + srow8) * CCH
                : aV + (size_t)((slab - 8) * 8 + srow8) * CCH;
            GLOAD_LDS16(ab + k0 + scs, sh + slab * 512);
            GLOAD_LDS16(bBase + (size_t)(slab * 8 + srow8) * CCH + k0 + scs,
                        sh + 8192 + slab * 512);
        }
        __syncthreads();
        #pragma unroll
        for (int kk = 0; kk < 2; ++kk) {
            const int sc8 = ((kk * 4 + quad) ^ lmp) * 8;
            short8 fw[4], fx[4];
            #pragma unroll
            for (int i = 0; i < 4; ++i)
                fw[i] = *(const short8*)(sh + (wo + i * 16 + lm) * 64 + sc8);
            #pragma unroll
            for (int j = 0; j < 4; ++j)
                fx[j] = *(const short8*)(sh + 8192 + (wn + j * 16 + lm) * 64 + sc8);
            #pragma unroll
            for (int i = 0; i < 4; ++i)
                #pragma unroll
                for (int j = 0; j < 4; ++j)
                    acc[i][j] = __builtin_amdgcn_mfma_f32_16x16x32_bf16(
                        fx[j], fw[i], acc[i][j], 0, 0, 0);
        }
    }

    // ---- epilogue 1: bias + phi(k), write bf16 tile [c][n] to LDS ----
    // acc: rows=n (quad*4+r), cols=c (lm); c = wo+i*16+lm (0..63 k, 64..127 v)
    // LDS tile: row c, 128 n = 16 chunks of 8 elems; phys chunk = lchunk^(c&15)
    __syncthreads();                                  // done reading As/Bs
    const bool isk = (wv < 2);                        // wo==0 -> k rows
    const float* bptr = bias + (isk ? 512 : 1024) + h * 64;
    float ksp[4] = {0.f, 0.f, 0.f, 0.f};
    #pragma unroll
    for (int i = 0; i < 4; ++i) {
        float bs = bptr[i * 16 + lm];
        int row = wo + i * 16 + lm;                   // 0..127
        #pragma unroll
        for (int j = 0; j < 4; ++j) {
            int n = wn + j * 16 + quad * 4;
            ushort4v pk;
            #pragma unroll
            for (int r = 0; r < 4; ++r) {
                float v = acc[i][j][r] + bs;
                if (isk) { v = phi_act(v); ksp[i] += v; }
                pk[r] = f2bf(v);
            }
            int idx = row * 128 + ((((n >> 3) ^ (row & 15)) << 3) | (n & 7));
            *(ushort4v*)(sh + idx) = pk;
        }
    }
    // ksum partials (fp32, pre-round) -> quad-reduce -> atomic
    if (isk) {
        #pragma unroll
        for (int i = 0; i < 4; ++i) {
            float s = ksp[i];
            s += __shfl_xor(s, 16);
            s += __shfl_xor(s, 32);
            if (quad == 0)
                atomicAdd(ksum + b * CCH + h * 64 + i * 16 + lm, s);
        }
    }
    __syncthreads();

    // ---- epilogue 2: kv partial over 128 n, stored [d][e] ----
    // mfma(v_frag rows=e, k_frag rows=d) -> rows=e (quad*4+r), cols=d (lm)
    const int wd = (wv >> 1) * 32, we = (wv & 1) * 32;
    float4v acc2[2][2];
    #pragma unroll
    for (int i = 0; i < 2; ++i)
        #pragma unroll
        for (int j = 0; j < 2; ++j) acc2[i][j] = {0.f, 0.f, 0.f, 0.f};

    #pragma unroll
    for (int ks = 0; ks < 4; ++ks) {
        short8 ka[2], vbf[2];
        #pragma unroll
        for (int i2 = 0; i2 < 2; ++i2) {
            int row = wd + i2 * 16 + lm;              // k rows 0..63
            ka[i2] = *(const short8*)(sh + row * 128 +
                                      (((ks * 4 + quad) ^ (row & 15)) << 3));
        }
        #pragma unroll
        for (int j2 = 0; j2 < 2; ++j2) {
            int row = 64 + we + j2 * 16 + lm;         // v rows 64..127
            vbf[j2] = *(const short8*)(sh + row * 128 +
                                       (((ks * 4 + quad) ^ (row & 15)) << 3));
        }
        #pragma unroll
        for (int i2 = 0; i2 < 2; ++i2)
            #pragma unroll
            for (int j2 = 0; j2 < 2; ++j2)
                acc2[i2][j2] = __builtin_amdgcn_mfma_f32_16x16x32_bf16(
                    vbf[j2], ka[i2], acc2[i2][j2], 0, 0, 0);
    }

    // lane holds [e = we+j2*16+quad*4+r][d = wd+i2*16+lm] -> float4 over e.
    const int chunk = blockIdx.x;
    const int bh = b * 8 + h;
    #pragma unroll
    for (int i2 = 0; i2 < 2; ++i2)
        #pragma unroll
        for (int j2 = 0; j2 < 2; ++j2) {
            int d = wd + i2 * 16 + lm;
            int e = we + j2 * 16 + quad * 4;
            float4 r = {acc2[i2][j2][0], acc2[i2][j2][1],
                        acc2[i2][j2][2], acc2[i2][j2][3]};
            *(float4*)(kvp + ((size_t)(chunk * 64 + bh) * 64 + d) * 64 + e) = r;
        }
}

// ---------------------------------------------------------------------------
// Kernel 6: reduce 32 chunk partials -> kvTb[bh][d][e] bf16.
__global__ __launch_bounds__(256) void kv_reduce(const float* __restrict__ kvp,
                                                 unsigned short* __restrict__ kvTb) {
    int idx4 = (blockIdx.x * 256 + threadIdx.x) * 4;   // over 64*64*64
    float4 s = {0.f, 0.f, 0.f, 0.f};
    #pragma unroll
    for (int p = 0; p < 32; ++p) {
        float4 v = *(const float4*)(kvp + (size_t)p * (64 * 64 * 64) + idx4);
        s.x += v.x; s.y += v.y; s.z += v.z; s.w += v.w;
    }
    ushort4v o = {f2bf(s.x), f2bf(s.y), f2bf(s.z), f2bf(s.w)};
    *(ushort4v*)(kvTb + idx4) = o;
}

// ---------------------------------------------------------------------------
// Kernel 7: fold kv into proj weights.
//   M_b[o][h*64+d] = sum_e kv_{b,h}[d][e] * W[o][h*64+e]   (bf16 out)
//   grid = (o-quarter 4, bh 64).  Per wave: 64d x 32o, 16 MFMA.
__global__ __launch_bounds__(256) void kv_w(const unsigned short* __restrict__ kvTb,
                                            const unsigned short* __restrict__ pwb,
                                            unsigned short* __restrict__ Mw) {
    const int os = blockIdx.x * 128;
    const int bh = blockIdx.y;
    const int b = bh >> 3, h = bh & 7;
    const int t = threadIdx.x;
    const int wv = t >> 6, ln = t & 63;
    const int quad = ln >> 4, lm = ln & 15;

    __shared__ __align__(16) unsigned short kvs[64 * 64];

    // stage kv[d][e] (8 KB) with chunk swizzle: phys chunk = c ^ (d&7)
    {
        int d = t >> 2, e0 = (t & 3) * 16;
        const unsigned short* src = kvTb + (size_t)bh * 4096 + d * 64 + e0;
        int c0 = e0 >> 3;
        ushort8 v0 = *(const ushort8*)(src);
        ushort8 v1 = *(const ushort8*)(src + 8);
        *(ushort8*)(kvs + d * 64 + ((c0 ^ (d & 7)) << 3))       = v0;
        *(ushort8*)(kvs + d * 64 + (((c0 + 1) ^ (d & 7)) << 3)) = v1;
    }
    __syncthreads();

    short8 ka[4][2];
    #pragma unroll
    for (int i = 0; i < 4; ++i)
        #pragma unroll
        for (int kk = 0; kk < 2; ++kk) {
            int d = i * 16 + lm;
            ka[i][kk] = *(const short8*)(kvs + d * 64 +
                        (((kk * 4 + quad) ^ (lm & 7)) << 3));
        }
    short8 fw[2][2];
    #pragma unroll
    for (int j = 0; j < 2; ++j)
        #pragma unroll
        for (int kk = 0; kk < 2; ++kk) {
            int o = os + wv * 32 + j * 16 + lm;
            fw[j][kk] = *(const short8*)(pwb + (size_t)o * CCH + h * 64 +
                                         kk * 32 + quad * 8);
        }

    float4v acc[4][2];
    #pragma unroll
    for (int i = 0; i < 4; ++i)
        #pragma unroll
        for (int j = 0; j < 2; ++j) acc[i][j] = {0.f, 0.f, 0.f, 0.f};
    #pragma unroll
    for (int kk = 0; kk < 2; ++kk)
        #pragma unroll
        for (int i = 0; i < 4; ++i)
            #pragma unroll
            for (int j = 0; j < 2; ++j)
                acc[i][j] = __builtin_amdgcn_mfma_f32_16x16x32_bf16(
                    ka[i][kk], fw[j][kk], acc[i][j], 0, 0, 0);

    // rows=d (quad*4+r), cols=o (lm): store 4 consecutive c at row o.
    #pragma unroll
    for (int i = 0; i < 4; ++i)
        #pragma unroll
        for (int j = 0; j < 2; ++j) {
            int o = os + wv * 32 + j * 16 + lm;
            int c = h * 64 + i * 16 + quad * 4;
            ushort4v pk;
            #pragma unroll
            for (int r = 0; r < 4; ++r) pk[r] = f2bf(acc[i][j][r]);
            *(ushort4v*)(Mw + ((size_t)b * CCH + o) * CCH + c) = pk;
        }
}

// ---------------------------------------------------------------------------
// Kernel 8: proj GEMM on qT with per-batch folded weights M_b (BK=64).
//   out[n][o] = (sum_c q[n][c] M_b[o][c]) / den[b][n] + bias[o] + resid
__global__ __launch_bounds__(256) void gemm_proj(const unsigned short* __restrict__ Mw,
                                                 const unsigned short* __restrict__ Bt,
                                                 const float* __restrict__ bias,
                                                 const float* __restrict__ den,
                                                 const float* __restrict__ resid,
                                                 float* __restrict__ outF) {
    const int n0 = blockIdx.x * 128;
    const int o0 = blockIdx.y * 128;
    const int b  = blockIdx.z;
    const int t  = threadIdx.x;
    const int wv = t >> 6, ln = t & 63;
    const int quad = ln >> 4, lm = ln & 15;
    const int wo = (wv >> 1) * 64, wn = (wv & 1) * 64;

    __shared__ __align__(16) unsigned short As[128 * 64];
    __shared__ __align__(16) unsigned short Bs[128 * 64];

    float4v acc[4][4];
    #pragma unroll
    for (int i = 0; i < 4; ++i)
        #pragma unroll
        for (int j = 0; j < 4; ++j) acc[i][j] = {0.f, 0.f, 0.f, 0.f};

    const unsigned short* aBase = Mw + ((size_t)b * CCH + o0) * CCH;
    const unsigned short* bBase = Bt + ((size_t)b * NSP + n0) * CCH;

    const int srow8 = ln >> 3;
    const int scs   = ((ln & 7) ^ srow8) * 8;
    const int lmp   = (lm & 7);

    for (int k0 = 0; k0 < CCH; k0 += 64) {
        __syncthreads();
        #pragma unroll
        for (int i = 0; i < 4; ++i) {
            int slab = wv + i * 4;
            GLOAD_LDS16(aBase + (size_t)(slab * 8 + srow8) * CCH + k0 + scs,
                        As + slab * 512);
            GLOAD_LDS16(bBase + (size_t)(slab * 8 + srow8) * CCH + k0 + scs,
                        Bs + slab * 512);
        }
        __syncthreads();
        #pragma unroll
        for (int kk = 0; kk < 2; ++kk) {
            const int sc8 = ((kk * 4 + quad) ^ lmp) * 8;
            short8 fw[4], fx[4];
            #pragma unroll
            for (int i = 0; i < 4; ++i)
                fw[i] = *(const short8*)(As + (wo + i * 16 + lm) * 64 + sc8);
            #pragma unroll
            for (int j = 0; j < 4; ++j)
                fx[j] = *(const short8*)(Bs + (wn + j * 16 + lm) * 64 + sc8);
            #pragma unroll
            for (int i = 0; i < 4; ++i)
                #pragma unroll
                for (int j = 0; j < 4; ++j)
                    acc[i][j] = __builtin_amdgcn_mfma_f32_16x16x32_bf16(
                        fx[j], fw[i], acc[i][j], 0, 0, 0);
        }
    }

    // rows=n (quad*4+r), cols=o (lm). den-divide + bias + resid epilogue.
    float4v rden[4];
    #pragma unroll
    for (int j = 0; j < 4; ++j) {
        float4 dn = *(const float4*)(den + (size_t)b * NSP + n0 + wn +
                                     j * 16 + quad * 4);
        rden[j][0] = 1.f / (dn.x + 1e-6f);
        rden[j][1] = 1.f / (dn.y + 1e-6f);
        rden[j][2] = 1.f / (dn.z + 1e-6f);
        rden[j][3] = 1.f / (dn.w + 1e-6f);
    }
    #pragma unroll
    for (int i = 0; i < 4; ++i) {
        int o = o0 + wo + i * 16 + lm;
        float bs = bias[o];
        #pragma unroll
        for (int j = 0; j < 4; ++j) {
            int n = n0 + wn + j * 16 + quad * 4;
            size_t off = ((size_t)b * CCH + o) * NSP + n;
            float4 rv = *(const float4*)(resid + off);
            float4 w = {acc[i][j][0] * rden[j][0] + bs + rv.x,
                        acc[i][j][1] * rden[j][1] + bs + rv.y,
                        acc[i][j][2] * rden[j][2] + bs + rv.z,
                        acc[i][j][3] * rden[j][3] + bs + rv.w};
            *(float4*)(outF + off) = w;
        }
    }
}

// ---------------------------------------------------------------------------
extern "C" void kernel_launch(void* const* d_in, const int* in_sizes, int n_in,
                              void* d_out, int out_size, void* d_ws, size_t ws_size,
                              hipStream_t stream) {
    const float* x      = (const float*)d_in[0];
    const float* gamma  = (const float*)d_in[1];
    const float* beta   = (const float*)d_in[2];
    const float* qkv_w  = (const float*)d_in[3];
    const float* qkv_b  = (const float*)d_in[4];
    const float* proj_w = (const float*)d_in[5];
    const float* proj_b = (const float*)d_in[6];
    float* out = (float*)d_out;

    // workspace layout (float units)
    float* ws   = (float*)d_ws;
    float* ss   = ws;                                   //    8192
    float* ksum = ss + 8192;                            //    4096
    float* den  = ksum + 4096;                          //   32768
    float* kvp  = den + 32768;                          // 32*64*64*64
    unsigned short* xnT  = (unsigned short*)(kvp + (size_t)32 * 64 * 64 * 64);
    unsigned short* qT   = xnT + (size_t)BATCH * NSP * CCH;
    unsigned short* kvTb = qT  + (size_t)BATCH * NSP * CCH;
    unsigned short* Mw   = kvTb + (size_t)64 * 64 * 64;
    unsigned short* wqb  = Mw + (size_t)BATCH * CCH * CCH;
    unsigned short* wpb  = wqb + (size_t)O1 * CCH;

    gn_stats<<<BATCH * NGROUPS, 256, 0, stream>>>(x, gamma, beta, ss);
    conv_w<<<(O1 * CCH + CCH * CCH) / 4 / 256, 256, 0, stream>>>(qkv_w, proj_w, wqb, wpb, ksum, den);
    xnT_kernel<<<dim3(NSP / 64, CCH / 64, BATCH), 256, 0, stream>>>(x, ss, xnT);

    gemm_kv<<<dim3(NSP / 128, NHEADS, BATCH), 256, 0, stream>>>(wqb, xnT, qkv_b, ksum, kvp);
    gemm_q <<<dim3(NSP / 128, 4, BATCH), 256, 0, stream>>>(wqb, xnT, qkv_b, ksum, qT, den);

    kv_reduce<<<256, 256, 0, stream>>>(kvp, kvTb);
    kv_w<<<dim3(4, 64), 256, 0, stream>>>(kvTb, wpb, Mw);

    gemm_proj<<<dim3(NSP / 128, CCH / 128, BATCH), 256, 0, stream>>>(
        Mw, qT, proj_b, den, x, out);
}